// Round 1
// baseline (1168.063 us; speedup 1.0000x reference)
//
#include <hip/hip_runtime.h>
#include <math.h>

// Problem constants
constexpr int Bsz  = 64;
constexpr int Tseq = 256;
constexpr int Cdim = 384;
constexpr int Hh   = 6;
constexpr int HSd  = 64;
constexpr int Mrows = Bsz * Tseq;        // 16384
constexpr int Cffn  = 4 * Cdim;          // 1536

// ---------------------------------------------------------------------------
// LayerNorm: one wave (64 lanes) per row of 384; 4 rows per 256-thread block.
// ---------------------------------------------------------------------------
__global__ __launch_bounds__(256) void ln_kernel(
    const float* __restrict__ x, const float* __restrict__ w,
    const float* __restrict__ b, float* __restrict__ out, int nrows) {
  int row  = blockIdx.x * 4 + (threadIdx.x >> 6);
  int lane = threadIdx.x & 63;
  if (row >= nrows) return;
  const float* xr = x + (size_t)row * Cdim;
  float v[6];
  float s = 0.f;
#pragma unroll
  for (int i = 0; i < 6; ++i) { v[i] = xr[lane + 64 * i]; s += v[i]; }
#pragma unroll
  for (int off = 32; off > 0; off >>= 1) s += __shfl_xor(s, off, 64);
  float mean = s * (1.f / Cdim);
  float sq = 0.f;
#pragma unroll
  for (int i = 0; i < 6; ++i) { float d = v[i] - mean; sq += d * d; }
#pragma unroll
  for (int off = 32; off > 0; off >>= 1) sq += __shfl_xor(sq, off, 64);
  float rstd = rsqrtf(sq * (1.f / Cdim) + 1e-5f);
  float* orow = out + (size_t)row * Cdim;
#pragma unroll
  for (int i = 0; i < 6; ++i) {
    int c = lane + 64 * i;
    orow[c] = (v[i] - mean) * rstd * w[c] + b[c];
  }
}

// ---------------------------------------------------------------------------
// FP32 tiled GEMM: C[M,N] = epilogue(A[M,K] @ B[K,N] + bias).
// 64x64 block tile, BK=16, 256 threads, 4x4 micro-tile per thread.
// BHEAD=1: B is per-64-column-block blocked (Wq/Wk/Wv [H,C,HS] layout):
//          tile base = Bm + (n0/64)*K*64, row stride 64.
// EPI: 0 = +bias, 1 = +bias+res, 2 = gelu_exact(+bias)
// ---------------------------------------------------------------------------
template <int EPI, int BHEAD>
__global__ __launch_bounds__(256) void gemm_kernel(
    const float* __restrict__ A, const float* __restrict__ Bm,
    const float* __restrict__ bias, const float* __restrict__ res,
    float* __restrict__ C, int M, int N, int K) {
  __shared__ float As[16][68];   // [k][m], padded for float4 alignment + banks
  __shared__ float Bs[16][64];   // [k][n]
  const int tid = threadIdx.x;
  const int tx = tid & 15, ty = tid >> 4;
  const int m0 = blockIdx.y * 64, n0 = blockIdx.x * 64;

  const float* Bbase = BHEAD ? (Bm + (size_t)(n0 >> 6) * K * 64) : (Bm + n0);
  const int bstride = BHEAD ? 64 : N;

  // A loader: thread loads float4 of row (tid>>2), cols k0+(tid&3)*4..+3
  const int a_m = tid >> 2;
  const int a_k = (tid & 3) * 4;
  // B loader: thread loads float4 of row k0+(tid>>4), cols (tid&15)*4..+3
  const int b_k = tid >> 4;
  const int b_n = (tid & 15) * 4;

  float acc[4][4] = {};

  for (int k0 = 0; k0 < K; k0 += 16) {
    float4 av = *(const float4*)&A[(size_t)(m0 + a_m) * K + k0 + a_k];
    float4 bv = *(const float4*)&Bbase[(size_t)(k0 + b_k) * bstride + b_n];
    __syncthreads();
    As[a_k + 0][a_m] = av.x;
    As[a_k + 1][a_m] = av.y;
    As[a_k + 2][a_m] = av.z;
    As[a_k + 3][a_m] = av.w;
    *(float4*)&Bs[b_k][b_n] = bv;
    __syncthreads();
#pragma unroll
    for (int kk = 0; kk < 16; ++kk) {
      float4 af = *(const float4*)&As[kk][ty * 4];
      float4 bf = *(const float4*)&Bs[kk][tx * 4];
      float a_[4] = {af.x, af.y, af.z, af.w};
      float b_[4] = {bf.x, bf.y, bf.z, bf.w};
#pragma unroll
      for (int i = 0; i < 4; ++i)
#pragma unroll
        for (int j = 0; j < 4; ++j) acc[i][j] += a_[i] * b_[j];
    }
  }

  const int ncol = n0 + tx * 4;
  float4 bias4 = *(const float4*)&bias[ncol];
  float bb[4] = {bias4.x, bias4.y, bias4.z, bias4.w};
#pragma unroll
  for (int i = 0; i < 4; ++i) {
    int row = m0 + ty * 4 + i;
    float v[4];
#pragma unroll
    for (int j = 0; j < 4; ++j) v[j] = acc[i][j] + bb[j];
    if (EPI == 1) {
      float4 r4 = *(const float4*)&res[(size_t)row * N + ncol];
      v[0] += r4.x; v[1] += r4.y; v[2] += r4.z; v[3] += r4.w;
    } else if (EPI == 2) {
#pragma unroll
      for (int j = 0; j < 4; ++j)
        v[j] = 0.5f * v[j] * (1.f + erff(v[j] * 0.70710678118654752f));
    }
    float4 o4 = {v[0], v[1], v[2], v[3]};
    *(float4*)&C[(size_t)row * N + ncol] = o4;
  }
}

// ---------------------------------------------------------------------------
// Causal attention, one block per (b,h), 256 threads = one row t per thread.
// Per-thread online softmax; K/V staged in 64-row LDS tiles (32 KB total).
// Q/K/V read from concat layout [B,T,C] (col = h*64+d); O written same way.
// ---------------------------------------------------------------------------
__global__ __launch_bounds__(256) void attn_kernel(
    const float* __restrict__ Qc, const float* __restrict__ Kc,
    const float* __restrict__ Vc, float* __restrict__ Oc) {
  __shared__ float Ks[64 * 64];
  __shared__ float Vs[64 * 64];
  const int b = blockIdx.x / Hh, h = blockIdx.x % Hh;
  const int tid = threadIdx.x;
  const int t = tid;
  const size_t rowbase = (size_t)b * Tseq * Cdim + h * HSd;

  const float* qg = Qc + rowbase + (size_t)t * Cdim;
  float4 q[16];
#pragma unroll
  for (int i = 0; i < 16; ++i) q[i] = *(const float4*)&qg[i * 4];

  float4 o[16];
#pragma unroll
  for (int i = 0; i < 16; ++i) o[i] = make_float4(0.f, 0.f, 0.f, 0.f);
  float mval = -1e30f, l = 0.f;
  const float scale = 0.125f;  // 1/sqrt(64)

  const float* Kg = Kc + rowbase;
  const float* Vg = Vc + rowbase;

  for (int tile = 0; tile < Tseq / 64; ++tile) {
    __syncthreads();
    for (int e = tid; e < 64 * 16; e += 256) {
      int s = e >> 4, d4 = e & 15;
      ((float4*)Ks)[e] = *(const float4*)&Kg[(size_t)(tile * 64 + s) * Cdim + d4 * 4];
      ((float4*)Vs)[e] = *(const float4*)&Vg[(size_t)(tile * 64 + s) * Cdim + d4 * 4];
    }
    __syncthreads();
    int smax = t - tile * 64;
    if (smax > 63) smax = 63;
    for (int ss = 0; ss <= smax; ++ss) {
      const float4* kr = (const float4*)(Ks + ss * 64);
      float dot = 0.f;
#pragma unroll
      for (int i = 0; i < 16; ++i) {
        float4 kv = kr[i];
        dot += q[i].x * kv.x + q[i].y * kv.y + q[i].z * kv.z + q[i].w * kv.w;
      }
      dot *= scale;
      float mnew = fmaxf(mval, dot);
      float alpha = __expf(mval - mnew);
      float p = __expf(dot - mnew);
      l = l * alpha + p;
      const float4* vr = (const float4*)(Vs + ss * 64);
#pragma unroll
      for (int i = 0; i < 16; ++i) {
        float4 vv = vr[i];
        o[i].x = o[i].x * alpha + p * vv.x;
        o[i].y = o[i].y * alpha + p * vv.y;
        o[i].z = o[i].z * alpha + p * vv.z;
        o[i].w = o[i].w * alpha + p * vv.w;
      }
      mval = mnew;
    }
  }
  float inv = 1.f / l;
  float* og = Oc + rowbase + (size_t)t * Cdim;
#pragma unroll
  for (int i = 0; i < 16; ++i) {
    float4 ov = o[i];
    ov.x *= inv; ov.y *= inv; ov.z *= inv; ov.w *= inv;
    *(float4*)&og[i * 4] = ov;
  }
}

// ---------------------------------------------------------------------------
extern "C" void kernel_launch(void* const* d_in, const int* in_sizes, int n_in,
                              void* d_out, int out_size, void* d_ws, size_t ws_size,
                              hipStream_t stream) {
  const float* x      = (const float*)d_in[0];
  const float* ln1_w  = (const float*)d_in[1];
  const float* ln1_b  = (const float*)d_in[2];
  const float* Wq     = (const float*)d_in[3];
  const float* bq     = (const float*)d_in[4];
  const float* Wk     = (const float*)d_in[5];
  const float* bk     = (const float*)d_in[6];
  const float* Wv     = (const float*)d_in[7];
  const float* bv     = (const float*)d_in[8];
  const float* Wproj  = (const float*)d_in[9];
  const float* bproj  = (const float*)d_in[10];
  const float* ln2_w  = (const float*)d_in[11];
  const float* ln2_b  = (const float*)d_in[12];
  const float* W1     = (const float*)d_in[13];
  const float* b1     = (const float*)d_in[14];
  const float* W2     = (const float*)d_in[15];
  const float* b2     = (const float*)d_in[16];
  float* out = (float*)d_out;

  // Workspace layout: 6 units of M*C floats = 144 MB, with reuse.
  const size_t U = (size_t)Mrows * Cdim;  // 6291456 floats
  float* ws = (float*)d_ws;
  float* hbuf = ws + 0 * U;   // LN1 out;  later reused for x1
  float* Qc   = ws + 1 * U;   // later reused for h2
  float* Kc   = ws + 2 * U;   // later start of g (4 units: 2..5)
  float* Vc   = ws + 3 * U;
  float* Oc   = ws + 4 * U;
  float* x1   = hbuf;
  float* h2   = Qc;
  float* g    = Kc;

  dim3 blk(256);

  // 1. LN1
  ln_kernel<<<dim3(Mrows / 4), blk, 0, stream>>>(x, ln1_w, ln1_b, hbuf, Mrows);

  // 2. Q, K, V  (M=16384, N=384, K=384; per-head-blocked B)
  {
    dim3 grid(Cdim / 64, Mrows / 64);
    gemm_kernel<0, 1><<<grid, blk, 0, stream>>>(hbuf, Wq, bq, nullptr, Qc,
                                                Mrows, Cdim, Cdim);
    gemm_kernel<0, 1><<<grid, blk, 0, stream>>>(hbuf, Wk, bk, nullptr, Kc,
                                                Mrows, Cdim, Cdim);
    gemm_kernel<0, 1><<<grid, blk, 0, stream>>>(hbuf, Wv, bv, nullptr, Vc,
                                                Mrows, Cdim, Cdim);
  }

  // 3. Attention (causal, online softmax)
  attn_kernel<<<dim3(Bsz * Hh), blk, 0, stream>>>(Qc, Kc, Vc, Oc);

  // 4. x1 = x + Oc @ Wproj + bproj
  gemm_kernel<1, 0><<<dim3(Cdim / 64, Mrows / 64), blk, 0, stream>>>(
      Oc, Wproj, bproj, x, x1, Mrows, Cdim, Cdim);

  // 5. LN2
  ln_kernel<<<dim3(Mrows / 4), blk, 0, stream>>>(x1, ln2_w, ln2_b, h2, Mrows);

  // 6. g = gelu(h2 @ W1 + b1)   (N=1536)
  gemm_kernel<2, 0><<<dim3(Cffn / 64, Mrows / 64), blk, 0, stream>>>(
      h2, W1, b1, nullptr, g, Mrows, Cffn, Cdim);

  // 7. out = x1 + g @ W2 + b2   (K=1536)
  gemm_kernel<1, 0><<<dim3(Cdim / 64, Mrows / 64), blk, 0, stream>>>(
      g, W2, b2, x1, out, Mrows, Cdim, Cffn);
}

// Round 2
// 386.132 us; speedup vs baseline: 3.0250x; 3.0250x over previous
//
#include <hip/hip_runtime.h>
#include <math.h>

// Problem constants
constexpr int Bsz  = 64;
constexpr int Tseq = 256;
constexpr int Cdim = 384;
constexpr int Hh   = 6;
constexpr int HSd  = 64;
constexpr int Mrows = Bsz * Tseq;        // 16384
constexpr int Cffn  = 4 * Cdim;          // 1536
constexpr int Nqkv  = 3 * Cdim;          // 1152

typedef __attribute__((ext_vector_type(8))) short short8;  // 8 bf16 = 4 VGPRs
typedef __attribute__((ext_vector_type(4))) float f32x4;

// fp32 -> bf16 round-to-nearest-even
__device__ __forceinline__ ushort f2bf(float x) {
  union { float f; uint u; } a; a.f = x;
  uint r = a.u + 0x7fffu + ((a.u >> 16) & 1u);
  return (ushort)(r >> 16);
}
// two packed bf16 (in one uint) + two more -> float4
__device__ __forceinline__ float4 bf4(uint a, uint b) {
  union { uint u; float f; } x0, x1, x2, x3;
  x0.u = a << 16; x1.u = a & 0xffff0000u;
  x2.u = b << 16; x3.u = b & 0xffff0000u;
  return make_float4(x0.f, x1.f, x2.f, x3.f);
}

// ---------------------------------------------------------------------------
// Batched transpose + cast: in fp32 [Bn][R][S] -> out bf16 [Bn][S][R]
// ---------------------------------------------------------------------------
__global__ __launch_bounds__(256) void tcast_kernel(
    const float* __restrict__ in, ushort* __restrict__ out, int R, int S) {
  __shared__ float t[32][33];
  int bn = blockIdx.z;
  in  += (size_t)bn * R * S;
  out += (size_t)bn * R * S;
  int s0 = blockIdx.x * 32, r0 = blockIdx.y * 32;
  int tx = threadIdx.x, ty = threadIdx.y;  // 32 x 8
#pragma unroll
  for (int i = 0; i < 32; i += 8)
    t[ty + i][tx] = in[(size_t)(r0 + ty + i) * S + s0 + tx];
  __syncthreads();
#pragma unroll
  for (int i = 0; i < 32; i += 8)
    out[(size_t)(s0 + ty + i) * R + r0 + tx] = f2bf(t[tx][ty + i]);
}

__global__ __launch_bounds__(256) void bias_concat_kernel(
    const float* __restrict__ bq, const float* __restrict__ bk,
    const float* __restrict__ bv, float* __restrict__ out) {
  int i = blockIdx.x * 256 + threadIdx.x;
  if (i >= Nqkv) return;
  out[i] = (i < 384) ? bq[i] : (i < 768) ? bk[i - 384] : bv[i - 768];
}

// ---------------------------------------------------------------------------
// LayerNorm: one wave per row of 384; 4 rows per block. bf16 output.
// ---------------------------------------------------------------------------
__global__ __launch_bounds__(256) void ln_kernel(
    const float* __restrict__ x, const float* __restrict__ w,
    const float* __restrict__ b, ushort* __restrict__ out, int nrows) {
  int row  = blockIdx.x * 4 + (threadIdx.x >> 6);
  int lane = threadIdx.x & 63;
  if (row >= nrows) return;
  const float* xr = x + (size_t)row * Cdim;
  float v[6];
  float s = 0.f;
#pragma unroll
  for (int i = 0; i < 6; ++i) { v[i] = xr[lane + 64 * i]; s += v[i]; }
#pragma unroll
  for (int off = 32; off > 0; off >>= 1) s += __shfl_xor(s, off, 64);
  float mean = s * (1.f / Cdim);
  float sq = 0.f;
#pragma unroll
  for (int i = 0; i < 6; ++i) { float d = v[i] - mean; sq += d * d; }
#pragma unroll
  for (int off = 32; off > 0; off >>= 1) sq += __shfl_xor(sq, off, 64);
  float rstd = rsqrtf(sq * (1.f / Cdim) + 1e-5f);
  ushort* orow = out + (size_t)row * Cdim;
#pragma unroll
  for (int i = 0; i < 6; ++i) {
    int c = lane + 64 * i;
    orow[c] = f2bf((v[i] - mean) * rstd * w[c] + b[c]);
  }
}

// ---------------------------------------------------------------------------
// bf16 MFMA GEMM (m97 structure): C[M,N] = epi(A[M,K] @ Bt[N,K]^T + bias).
// 128x128 tile, BK=32, 256 threads (4 waves, 2x2 of 64x64), 4x4 16x16 tiles
// per wave. global_load_lds width-16 staging; LDS [128][32] bf16 for A and Bt.
// EPI: 0 = +bias -> bf16 out; 1 = +bias+res -> fp32 out; 2 = gelu -> bf16 out
// ---------------------------------------------------------------------------
template <int EPI>
__global__ __launch_bounds__(256) void mfma_gemm(
    const ushort* __restrict__ A, const ushort* __restrict__ Bt,
    const float* __restrict__ bias, const float* __restrict__ res,
    void* __restrict__ Cout, int M, int N, int K) {
  __shared__ ushort Als[128 * 32];
  __shared__ ushort Bls[128 * 32];
  const int tid = threadIdx.x;
  const int m0 = blockIdx.y * 128, n0 = blockIdx.x * 128;

  const int lane = tid & 63;
  const int w    = tid >> 6;
  const int wr   = (w >> 1) * 64;   // wave row origin in tile
  const int wc   = (w & 1) * 64;    // wave col origin in tile
  const int lm   = lane & 15;       // row/col within 16x16
  const int kq   = (lane >> 4) * 8; // k-chunk for A/B frags
  const int rq   = (lane >> 4) * 4; // row base for C/D

  // staging chunks: 16B each; chunk c covers row c/4, cols (c%4)*8..+7 (bf16)
  const int c0 = tid, c1 = tid + 256;
  const int wbase = (tid & ~63) * 8;  // ushort offset of this wave's chunk run

  f32x4 acc[4][4] = {};

  for (int k0 = 0; k0 < K; k0 += 32) {
    const ushort* gA0 = A  + (size_t)(m0 + (c0 >> 2)) * K + k0 + (c0 & 3) * 8;
    const ushort* gA1 = A  + (size_t)(m0 + (c1 >> 2)) * K + k0 + (c1 & 3) * 8;
    const ushort* gB0 = Bt + (size_t)(n0 + (c0 >> 2)) * K + k0 + (c0 & 3) * 8;
    const ushort* gB1 = Bt + (size_t)(n0 + (c1 >> 2)) * K + k0 + (c1 & 3) * 8;
    __syncthreads();  // protect LDS from overwrite while prior iter reads
    __builtin_amdgcn_global_load_lds(
        (const __attribute__((address_space(1))) uint*)gA0,
        (__attribute__((address_space(3))) uint*)(Als + wbase), 16, 0, 0);
    __builtin_amdgcn_global_load_lds(
        (const __attribute__((address_space(1))) uint*)gA1,
        (__attribute__((address_space(3))) uint*)(Als + wbase + 2048), 16, 0, 0);
    __builtin_amdgcn_global_load_lds(
        (const __attribute__((address_space(1))) uint*)gB0,
        (__attribute__((address_space(3))) uint*)(Bls + wbase), 16, 0, 0);
    __builtin_amdgcn_global_load_lds(
        (const __attribute__((address_space(1))) uint*)gB1,
        (__attribute__((address_space(3))) uint*)(Bls + wbase + 2048), 16, 0, 0);
    __syncthreads();  // drains vmcnt -> staging visible

    short8 af[4], bf[4];
#pragma unroll
    for (int i = 0; i < 4; ++i)
      af[i] = *(const short8*)&Als[(wr + i * 16 + lm) * 32 + kq];
#pragma unroll
    for (int j = 0; j < 4; ++j)
      bf[j] = *(const short8*)&Bls[(wc + j * 16 + lm) * 32 + kq];
#pragma unroll
    for (int i = 0; i < 4; ++i)
#pragma unroll
      for (int j = 0; j < 4; ++j)
        acc[i][j] = __builtin_amdgcn_mfma_f32_16x16x32_bf16(af[i], bf[j],
                                                            acc[i][j], 0, 0, 0);
  }

#pragma unroll
  for (int j = 0; j < 4; ++j) {
    const int col = n0 + wc + j * 16 + lm;
    const float bj = bias[col];
#pragma unroll
    for (int i = 0; i < 4; ++i) {
#pragma unroll
      for (int r = 0; r < 4; ++r) {
        const int row = m0 + wr + i * 16 + rq + r;
        float v = acc[i][j][r] + bj;
        if (EPI == 1) {
          v += res[(size_t)row * N + col];
          ((float*)Cout)[(size_t)row * N + col] = v;
        } else if (EPI == 2) {
          v = 0.5f * v * (1.f + erff(v * 0.70710678118654752f));
          ((ushort*)Cout)[(size_t)row * N + col] = f2bf(v);
        } else {
          ((ushort*)Cout)[(size_t)row * N + col] = f2bf(v);
        }
      }
    }
  }
}

// ---------------------------------------------------------------------------
// Causal attention. Block = (b, h, q-tile of 64 rows); 256 threads =
// 64 rows x 4 d-quarters (16 dims each). Quad shfl_xor reduces the QK dot.
// QKV packed bf16 [M][1152] (Q cols 0..383, K 384.., V 768.., col h*64+d).
// Output Oc bf16 [M][384] in concat layout.
// ---------------------------------------------------------------------------
__global__ __launch_bounds__(256) void attn_kernel(
    const ushort* __restrict__ qkv, ushort* __restrict__ Oc) {
  __shared__ float Ks[64 * 64];
  __shared__ float Vs[64 * 64];
  const int bh = blockIdx.x, qt = blockIdx.y;
  const int b = bh / Hh, h = bh % Hh;
  const int tid = threadIdx.x;
  const int rl = tid >> 2;   // row within q-tile
  const int dq = tid & 3;    // 16-dim quarter
  const int t = qt * 64 + rl;

  const ushort* qg = qkv + ((size_t)(b * Tseq + t)) * Nqkv + h * HSd + dq * 16;
  float4 q4[4];
  {
    uint4 u0 = *(const uint4*)qg;
    uint4 u1 = *(const uint4*)(qg + 8);
    q4[0] = bf4(u0.x, u0.y); q4[1] = bf4(u0.z, u0.w);
    q4[2] = bf4(u1.x, u1.y); q4[3] = bf4(u1.z, u1.w);
  }
  float4 o[4];
#pragma unroll
  for (int i = 0; i < 4; ++i) o[i] = make_float4(0.f, 0.f, 0.f, 0.f);
  float mval = -1e30f, l = 0.f;

  const ushort* Kbase = qkv + (size_t)b * Tseq * Nqkv + Cdim + h * HSd;
  const ushort* Vbase = qkv + (size_t)b * Tseq * Nqkv + 2 * Cdim + h * HSd;

  for (int st = 0; st <= qt; ++st) {
    __syncthreads();
    for (int c = tid; c < 512; c += 256) {
      int r = c >> 3, c8 = (c & 7) * 8;
      uint4 uk = *(const uint4*)&Kbase[(size_t)(st * 64 + r) * Nqkv + c8];
      uint4 uv = *(const uint4*)&Vbase[(size_t)(st * 64 + r) * Nqkv + c8];
      ((float4*)(Ks + r * 64 + c8))[0] = bf4(uk.x, uk.y);
      ((float4*)(Ks + r * 64 + c8))[1] = bf4(uk.z, uk.w);
      ((float4*)(Vs + r * 64 + c8))[0] = bf4(uv.x, uv.y);
      ((float4*)(Vs + r * 64 + c8))[1] = bf4(uv.z, uv.w);
    }
    __syncthreads();
    const int smax = (st == qt) ? rl : 63;
    for (int ss = 0; ss <= smax; ++ss) {
      const float4* kr = (const float4*)(Ks + ss * 64 + dq * 16);
      float p = 0.f;
#pragma unroll
      for (int i = 0; i < 4; ++i) {
        float4 kv = kr[i];
        p += q4[i].x * kv.x + q4[i].y * kv.y + q4[i].z * kv.z + q4[i].w * kv.w;
      }
      p += __shfl_xor(p, 1, 64);
      p += __shfl_xor(p, 2, 64);
      p *= 0.125f;  // 1/sqrt(64)
      float mnew = fmaxf(mval, p);
      float alpha = __expf(mval - mnew);
      float pe = __expf(p - mnew);
      l = l * alpha + pe;
      const float4* vr = (const float4*)(Vs + ss * 64 + dq * 16);
#pragma unroll
      for (int i = 0; i < 4; ++i) {
        float4 vv = vr[i];
        o[i].x = o[i].x * alpha + pe * vv.x;
        o[i].y = o[i].y * alpha + pe * vv.y;
        o[i].z = o[i].z * alpha + pe * vv.z;
        o[i].w = o[i].w * alpha + pe * vv.w;
      }
      mval = mnew;
    }
  }
  const float inv = 1.f / l;
  ushort tmp[16];
#pragma unroll
  for (int i = 0; i < 4; ++i) {
    tmp[i * 4 + 0] = f2bf(o[i].x * inv);
    tmp[i * 4 + 1] = f2bf(o[i].y * inv);
    tmp[i * 4 + 2] = f2bf(o[i].z * inv);
    tmp[i * 4 + 3] = f2bf(o[i].w * inv);
  }
  ushort* og = Oc + ((size_t)(b * Tseq + t)) * Cdim + h * HSd + dq * 16;
  uint4 p0, p1;
  p0.x = tmp[0] | (tmp[1] << 16);   p0.y = tmp[2] | (tmp[3] << 16);
  p0.z = tmp[4] | (tmp[5] << 16);   p0.w = tmp[6] | (tmp[7] << 16);
  p1.x = tmp[8] | (tmp[9] << 16);   p1.y = tmp[10] | (tmp[11] << 16);
  p1.z = tmp[12] | (tmp[13] << 16); p1.w = tmp[14] | (tmp[15] << 16);
  *(uint4*)og = p0;
  *(uint4*)(og + 8) = p1;
}

// ---------------------------------------------------------------------------
extern "C" void kernel_launch(void* const* d_in, const int* in_sizes, int n_in,
                              void* d_out, int out_size, void* d_ws, size_t ws_size,
                              hipStream_t stream) {
  const float* x      = (const float*)d_in[0];
  const float* ln1_w  = (const float*)d_in[1];
  const float* ln1_b  = (const float*)d_in[2];
  const float* Wq     = (const float*)d_in[3];
  const float* bq     = (const float*)d_in[4];
  const float* Wk     = (const float*)d_in[5];
  const float* bk     = (const float*)d_in[6];
  const float* Wv     = (const float*)d_in[7];
  const float* bv     = (const float*)d_in[8];
  const float* Wproj  = (const float*)d_in[9];
  const float* bproj  = (const float*)d_in[10];
  const float* ln2_w  = (const float*)d_in[11];
  const float* ln2_b  = (const float*)d_in[12];
  const float* W1     = (const float*)d_in[13];
  const float* b1     = (const float*)d_in[14];
  const float* W2     = (const float*)d_in[15];
  const float* b2     = (const float*)d_in[16];
  float* out = (float*)d_out;

  // Workspace layout (bytes), total ~111 MB (< the 144 MB proven in R0):
  char* p = (char*)d_ws;
  ushort* h     = (ushort*)p;  p += (size_t)Mrows * Cdim * 2;   // 12.6 MB, reused as h2
  ushort* qkv   = (ushort*)p;                                    // 37.7 MB
  float*  x1    = (float*)p;   p += (size_t)Mrows * Nqkv * 2;   // x1 (25 MB) aliases qkv
  ushort* Oc    = (ushort*)p;  p += (size_t)Mrows * Cdim * 2;   // 12.6 MB
  ushort* g     = (ushort*)p;  p += (size_t)Mrows * Cffn * 2;   // 50.3 MB
  ushort* WqkvT = (ushort*)p;  p += (size_t)Nqkv * Cdim * 2;
  ushort* WprojT= (ushort*)p;  p += (size_t)Cdim * Cdim * 2;
  ushort* W1T   = (ushort*)p;  p += (size_t)Cffn * Cdim * 2;
  ushort* W2T   = (ushort*)p;  p += (size_t)Cdim * Cffn * 2;
  float*  bqkv  = (float*)p;   p += (size_t)Nqkv * 4;
  ushort* h2 = h;

  dim3 blk(256);
  dim3 tblk(32, 8);

  // Weight transpose-casts to bf16 [N][K]
  tcast_kernel<<<dim3(2, 12, 6), tblk, 0, stream>>>(Wq, WqkvT,            384, 64);
  tcast_kernel<<<dim3(2, 12, 6), tblk, 0, stream>>>(Wk, WqkvT + 384*384,  384, 64);
  tcast_kernel<<<dim3(2, 12, 6), tblk, 0, stream>>>(Wv, WqkvT + 768*384,  384, 64);
  tcast_kernel<<<dim3(12, 12, 1), tblk, 0, stream>>>(Wproj, WprojT, 384, 384);
  tcast_kernel<<<dim3(48, 12, 1), tblk, 0, stream>>>(W1, W1T, 384, 1536);
  tcast_kernel<<<dim3(12, 48, 1), tblk, 0, stream>>>(W2, W2T, 1536, 384);
  bias_concat_kernel<<<dim3(5), blk, 0, stream>>>(bq, bk, bv, bqkv);

  // 1. LN1 -> h (bf16)
  ln_kernel<<<dim3(Mrows / 4), blk, 0, stream>>>(x, ln1_w, ln1_b, h, Mrows);

  // 2. QKV fused GEMM: [M,1152] bf16
  mfma_gemm<0><<<dim3(Nqkv / 128, Mrows / 128), blk, 0, stream>>>(
      h, WqkvT, bqkv, nullptr, qkv, Mrows, Nqkv, Cdim);

  // 3. Attention -> Oc (bf16)
  attn_kernel<<<dim3(Bsz * Hh, 4), blk, 0, stream>>>(qkv, Oc);

  // 4. x1 = x + Oc @ Wproj + bproj (fp32)
  mfma_gemm<1><<<dim3(Cdim / 128, Mrows / 128), blk, 0, stream>>>(
      Oc, WprojT, bproj, x, x1, Mrows, Cdim, Cdim);

  // 5. LN2 -> h2 (bf16)
  ln_kernel<<<dim3(Mrows / 4), blk, 0, stream>>>(x1, ln2_w, ln2_b, h2, Mrows);

  // 6. g = gelu(h2 @ W1 + b1) (bf16)
  mfma_gemm<2><<<dim3(Cffn / 128, Mrows / 128), blk, 0, stream>>>(
      h2, W1T, b1, nullptr, g, Mrows, Cffn, Cdim);

  // 7. out = x1 + g @ W2 + b2 (fp32)
  mfma_gemm<1><<<dim3(Cdim / 128, Mrows / 128), blk, 0, stream>>>(
      g, W2T, b2, x1, out, Mrows, Cdim, Cffn);
}

// Round 3
// 311.176 us; speedup vs baseline: 3.7537x; 1.2409x over previous
//
#include <hip/hip_runtime.h>
#include <math.h>

// Problem constants
constexpr int Bsz  = 64;
constexpr int Tseq = 256;
constexpr int Cdim = 384;
constexpr int Hh   = 6;
constexpr int HSd  = 64;
constexpr int Mrows = Bsz * Tseq;        // 16384
constexpr int Cffn  = 4 * Cdim;          // 1536
constexpr int Nqkv  = 3 * Cdim;          // 1152

typedef __attribute__((ext_vector_type(8))) short short8;  // 8 bf16 = 4 VGPRs
typedef __attribute__((ext_vector_type(4))) float f32x4;

// fp32 -> bf16 round-to-nearest-even
__device__ __forceinline__ ushort f2bf(float x) {
  union { float f; uint u; } a; a.f = x;
  uint r = a.u + 0x7fffu + ((a.u >> 16) & 1u);
  return (ushort)(r >> 16);
}

// ---------------------------------------------------------------------------
// Batched transpose + cast: in fp32 [Bn][R][S] -> out bf16 [Bn][S][R]
// ---------------------------------------------------------------------------
__global__ __launch_bounds__(256) void tcast_kernel(
    const float* __restrict__ in, ushort* __restrict__ out, int R, int S) {
  __shared__ float t[32][33];
  int bn = blockIdx.z;
  in  += (size_t)bn * R * S;
  out += (size_t)bn * R * S;
  int s0 = blockIdx.x * 32, r0 = blockIdx.y * 32;
  int tx = threadIdx.x, ty = threadIdx.y;  // 32 x 8
#pragma unroll
  for (int i = 0; i < 32; i += 8)
    t[ty + i][tx] = in[(size_t)(r0 + ty + i) * S + s0 + tx];
  __syncthreads();
#pragma unroll
  for (int i = 0; i < 32; i += 8)
    out[(size_t)(s0 + ty + i) * R + r0 + tx] = f2bf(t[tx][ty + i]);
}

__global__ __launch_bounds__(256) void bias_concat_kernel(
    const float* __restrict__ bq, const float* __restrict__ bk,
    const float* __restrict__ bv, float* __restrict__ out) {
  int i = blockIdx.x * 256 + threadIdx.x;
  if (i >= Nqkv) return;
  out[i] = (i < 384) ? bq[i] : (i < 768) ? bk[i - 384] : bv[i - 768];
}

// ---------------------------------------------------------------------------
// LayerNorm: one wave per row of 384; 4 rows per block. bf16 output.
// ---------------------------------------------------------------------------
__global__ __launch_bounds__(256) void ln_kernel(
    const float* __restrict__ x, const float* __restrict__ w,
    const float* __restrict__ b, ushort* __restrict__ out, int nrows) {
  int row  = blockIdx.x * 4 + (threadIdx.x >> 6);
  int lane = threadIdx.x & 63;
  if (row >= nrows) return;
  const float* xr = x + (size_t)row * Cdim;
  float v[6];
  float s = 0.f;
#pragma unroll
  for (int i = 0; i < 6; ++i) { v[i] = xr[lane + 64 * i]; s += v[i]; }
#pragma unroll
  for (int off = 32; off > 0; off >>= 1) s += __shfl_xor(s, off, 64);
  float mean = s * (1.f / Cdim);
  float sq = 0.f;
#pragma unroll
  for (int i = 0; i < 6; ++i) { float d = v[i] - mean; sq += d * d; }
#pragma unroll
  for (int off = 32; off > 0; off >>= 1) sq += __shfl_xor(sq, off, 64);
  float rstd = rsqrtf(sq * (1.f / Cdim) + 1e-5f);
  ushort* orow = out + (size_t)row * Cdim;
#pragma unroll
  for (int i = 0; i < 6; ++i) {
    int c = lane + 64 * i;
    orow[c] = f2bf((v[i] - mean) * rstd * w[c] + b[c]);
  }
}

// ---------------------------------------------------------------------------
// bf16 MFMA GEMM (m97 structure): C[M,N] = epi(A[M,K] @ Bt[N,K]^T + bias).
// 128x128 tile, BK=32, 256 threads (4 waves, 2x2 of 64x64), 4x4 16x16 tiles
// per wave. global_load_lds width-16 staging; LDS [128][32] bf16 for A and Bt.
// EPI: 0 = +bias -> bf16 out; 1 = +bias+res -> fp32 out; 2 = gelu -> bf16 out
//      3 = QKV scatter: Q,K -> [BH][T][64] bf16; V -> [BH][64][T] bf16
// ---------------------------------------------------------------------------
template <int EPI>
__global__ __launch_bounds__(256) void mfma_gemm(
    const ushort* __restrict__ A, const ushort* __restrict__ Bt,
    const float* __restrict__ bias, const float* __restrict__ res,
    void* __restrict__ Cout, void* __restrict__ C2, void* __restrict__ C3,
    int M, int N, int K) {
  __shared__ ushort Als[128 * 32];
  __shared__ ushort Bls[128 * 32];
  const int tid = threadIdx.x;
  const int m0 = blockIdx.y * 128, n0 = blockIdx.x * 128;

  const int lane = tid & 63;
  const int w    = tid >> 6;
  const int wr   = (w >> 1) * 64;   // wave row origin in tile
  const int wc   = (w & 1) * 64;    // wave col origin in tile
  const int lm   = lane & 15;       // row/col within 16x16
  const int kq   = (lane >> 4) * 8; // k-chunk for A/B frags
  const int rq   = (lane >> 4) * 4; // row base for C/D

  const int c0 = tid, c1 = tid + 256;
  const int wbase = (tid & ~63) * 8;  // ushort offset of this wave's chunk run

  f32x4 acc[4][4] = {};

  for (int k0 = 0; k0 < K; k0 += 32) {
    const ushort* gA0 = A  + (size_t)(m0 + (c0 >> 2)) * K + k0 + (c0 & 3) * 8;
    const ushort* gA1 = A  + (size_t)(m0 + (c1 >> 2)) * K + k0 + (c1 & 3) * 8;
    const ushort* gB0 = Bt + (size_t)(n0 + (c0 >> 2)) * K + k0 + (c0 & 3) * 8;
    const ushort* gB1 = Bt + (size_t)(n0 + (c1 >> 2)) * K + k0 + (c1 & 3) * 8;
    __syncthreads();
    __builtin_amdgcn_global_load_lds(
        (const __attribute__((address_space(1))) uint*)gA0,
        (__attribute__((address_space(3))) uint*)(Als + wbase), 16, 0, 0);
    __builtin_amdgcn_global_load_lds(
        (const __attribute__((address_space(1))) uint*)gA1,
        (__attribute__((address_space(3))) uint*)(Als + wbase + 2048), 16, 0, 0);
    __builtin_amdgcn_global_load_lds(
        (const __attribute__((address_space(1))) uint*)gB0,
        (__attribute__((address_space(3))) uint*)(Bls + wbase), 16, 0, 0);
    __builtin_amdgcn_global_load_lds(
        (const __attribute__((address_space(1))) uint*)gB1,
        (__attribute__((address_space(3))) uint*)(Bls + wbase + 2048), 16, 0, 0);
    __syncthreads();

    short8 af[4], bf[4];
#pragma unroll
    for (int i = 0; i < 4; ++i)
      af[i] = *(const short8*)&Als[(wr + i * 16 + lm) * 32 + kq];
#pragma unroll
    for (int j = 0; j < 4; ++j)
      bf[j] = *(const short8*)&Bls[(wc + j * 16 + lm) * 32 + kq];
#pragma unroll
    for (int i = 0; i < 4; ++i)
#pragma unroll
      for (int j = 0; j < 4; ++j)
        acc[i][j] = __builtin_amdgcn_mfma_f32_16x16x32_bf16(af[i], bf[j],
                                                            acc[i][j], 0, 0, 0);
  }

#pragma unroll
  for (int j = 0; j < 4; ++j) {
    const int col = n0 + wc + j * 16 + lm;
    const float bj = bias[col];
#pragma unroll
    for (int i = 0; i < 4; ++i) {
#pragma unroll
      for (int r = 0; r < 4; ++r) {
        const int row = m0 + wr + i * 16 + rq + r;
        float v = acc[i][j][r] + bj;
        if (EPI == 1) {
          v += res[(size_t)row * N + col];
          ((float*)Cout)[(size_t)row * N + col] = v;
        } else if (EPI == 2) {
          v = 0.5f * v * (1.f + erff(v * 0.70710678118654752f));
          ((ushort*)Cout)[(size_t)row * N + col] = f2bf(v);
        } else if (EPI == 3) {
          const int bb = row >> 8, tt = row & 255;
          const int sec = col / 384, cc = col % 384;
          const int hh = cc >> 6, d = cc & 63;
          const int bhh = bb * Hh + hh;
          if (sec == 0)
            ((ushort*)Cout)[((size_t)bhh * Tseq + tt) * HSd + d] = f2bf(v);
          else if (sec == 1)
            ((ushort*)C2)[((size_t)bhh * Tseq + tt) * HSd + d] = f2bf(v);
          else
            ((ushort*)C3)[((size_t)bhh * HSd + d) * Tseq + tt] = f2bf(v);
        } else {
          ((ushort*)Cout)[(size_t)row * N + col] = f2bf(v);
        }
      }
    }
  }
}

// ---------------------------------------------------------------------------
// MFMA flash attention. Block = (b*H+h, q-tile of 64 rows), 4 waves; wave w
// owns the 16-row Q strip [qt*64+w*16, +16). Per K-tile (64 keys):
//   S strip = Q(16x64) K^T  via 4 col-tiles x 2 MFMAs (16x16x32 bf16)
//   online softmax on C-layout S (row r = reg r, lanes&15 = cols)
//   P -> per-wave LDS (C-layout -> A-layout round trip)
//   O += P V  via 4 dim-tiles x 2 MFMAs, V staged transposed [dim][key]
// Inputs: Qb,Kb bf16 [BH][T][64]; Vtb bf16 [BH][64][T]. Output Oc bf16 [M][384].
// ---------------------------------------------------------------------------
__global__ __launch_bounds__(256) void attn_kernel(
    const ushort* __restrict__ Qb, const ushort* __restrict__ Kb,
    const ushort* __restrict__ Vtb, ushort* __restrict__ Oc) {
  __shared__ ushort Ks[64 * 80];     // [key][dim], stride 80 spreads banks
  __shared__ ushort Vt[64 * 80];     // [dim][key]
  __shared__ ushort Pl[4][16 * 72];  // per-wave P strip [row][key], 144B rows
  const int bh = blockIdx.x, qt = blockIdx.y;
  const int b = bh / Hh, h = bh % Hh;
  const int tid = threadIdx.x;
  const int w = tid >> 6, lane = tid & 63;
  const int g = lane >> 4, n16 = lane & 15;

  // Q A-frags: lane holds row m=n16 of the strip, k-chunk g*8 (+32 for frag 1)
  const ushort* qrow = Qb + ((size_t)bh * Tseq + qt * 64 + w * 16 + n16) * HSd;
  short8 qf0 = *(const short8*)(qrow + g * 8);
  short8 qf1 = *(const short8*)(qrow + 32 + g * 8);

  f32x4 oacc[4] = {};   // O strip 16x64: dim-tile j, C-layout
  float m_r[4], l_r[4];
#pragma unroll
  for (int r = 0; r < 4; ++r) { m_r[r] = -1e30f; l_r[r] = 0.f; }

  const int t0 = qt * 64 + w * 16 + g * 4;  // + r = global query index

  const ushort* Ksrc = Kb + (size_t)bh * Tseq * HSd;
  const ushort* Vsrc = Vtb + (size_t)bh * HSd * Tseq;

  for (int st = 0; st <= qt; ++st) {
    __syncthreads();
    for (int c = tid; c < 512; c += 256) {
      int r = c >> 3, cc = (c & 7) * 8;
      *(uint4*)&Ks[r * 80 + cc] =
          *(const uint4*)&Ksrc[(size_t)(st * 64 + r) * HSd + cc];
      *(uint4*)&Vt[r * 80 + cc] =
          *(const uint4*)&Vsrc[(size_t)r * Tseq + st * 64 + cc];
    }
    __syncthreads();

    // S = Q K^T, 4 col tiles
    f32x4 s[4];
#pragma unroll
    for (int ct = 0; ct < 4; ++ct) {
      short8 kf0 = *(const short8*)&Ks[(ct * 16 + n16) * 80 + g * 8];
      short8 kf1 = *(const short8*)&Ks[(ct * 16 + n16) * 80 + 32 + g * 8];
      f32x4 z = {};
      z = __builtin_amdgcn_mfma_f32_16x16x32_bf16(qf0, kf0, z, 0, 0, 0);
      z = __builtin_amdgcn_mfma_f32_16x16x32_bf16(qf1, kf1, z, 0, 0, 0);
      s[ct] = z;
    }

    // scale + causal mask
#pragma unroll
    for (int ct = 0; ct < 4; ++ct) {
      const int s_col = st * 64 + ct * 16 + n16;
#pragma unroll
      for (int r = 0; r < 4; ++r) {
        float v = s[ct][r] * 0.125f;
        s[ct][r] = (s_col > t0 + r) ? -1e30f : v;
      }
    }

    // online softmax update per strip row
#pragma unroll
    for (int r = 0; r < 4; ++r) {
      float m = fmaxf(fmaxf(s[0][r], s[1][r]), fmaxf(s[2][r], s[3][r]));
      m = fmaxf(m, __shfl_xor(m, 1, 64));
      m = fmaxf(m, __shfl_xor(m, 2, 64));
      m = fmaxf(m, __shfl_xor(m, 4, 64));
      m = fmaxf(m, __shfl_xor(m, 8, 64));
      float mnew = fmaxf(m_r[r], m);
      float alpha = __expf(m_r[r] - mnew);
      m_r[r] = mnew;
      float ssum = 0.f;
#pragma unroll
      for (int ct = 0; ct < 4; ++ct) {
        float p = __expf(s[ct][r] - mnew);
        s[ct][r] = p;
        ssum += p;
      }
      ssum += __shfl_xor(ssum, 1, 64);
      ssum += __shfl_xor(ssum, 2, 64);
      ssum += __shfl_xor(ssum, 4, 64);
      ssum += __shfl_xor(ssum, 8, 64);
      l_r[r] = l_r[r] * alpha + ssum;
#pragma unroll
      for (int j = 0; j < 4; ++j) oacc[j][r] *= alpha;
    }

    // P (C-layout) -> per-wave LDS [row][key]
    ushort* pw = &Pl[w][0];
#pragma unroll
    for (int ct = 0; ct < 4; ++ct)
#pragma unroll
      for (int r = 0; r < 4; ++r)
        pw[(g * 4 + r) * 72 + ct * 16 + n16] = f2bf(s[ct][r]);

    // P A-frags + PV
    short8 pf0 = *(const short8*)&pw[n16 * 72 + g * 8];
    short8 pf1 = *(const short8*)&pw[n16 * 72 + 32 + g * 8];
#pragma unroll
    for (int j = 0; j < 4; ++j) {
      short8 vf0 = *(const short8*)&Vt[(j * 16 + n16) * 80 + g * 8];
      short8 vf1 = *(const short8*)&Vt[(j * 16 + n16) * 80 + 32 + g * 8];
      oacc[j] = __builtin_amdgcn_mfma_f32_16x16x32_bf16(pf0, vf0, oacc[j], 0, 0, 0);
      oacc[j] = __builtin_amdgcn_mfma_f32_16x16x32_bf16(pf1, vf1, oacc[j], 0, 0, 0);
    }
  }

  float inv[4];
#pragma unroll
  for (int r = 0; r < 4; ++r) inv[r] = 1.f / l_r[r];
  ushort* orow = Oc + ((size_t)(b * Tseq + qt * 64 + w * 16)) * Cdim + h * HSd;
#pragma unroll
  for (int j = 0; j < 4; ++j)
#pragma unroll
    for (int r = 0; r < 4; ++r)
      orow[(size_t)(g * 4 + r) * Cdim + j * 16 + n16] = f2bf(oacc[j][r] * inv[r]);
}

// ---------------------------------------------------------------------------
extern "C" void kernel_launch(void* const* d_in, const int* in_sizes, int n_in,
                              void* d_out, int out_size, void* d_ws, size_t ws_size,
                              hipStream_t stream) {
  const float* x      = (const float*)d_in[0];
  const float* ln1_w  = (const float*)d_in[1];
  const float* ln1_b  = (const float*)d_in[2];
  const float* Wq     = (const float*)d_in[3];
  const float* bq     = (const float*)d_in[4];
  const float* Wk     = (const float*)d_in[5];
  const float* bk     = (const float*)d_in[6];
  const float* Wv     = (const float*)d_in[7];
  const float* bv     = (const float*)d_in[8];
  const float* Wproj  = (const float*)d_in[9];
  const float* bproj  = (const float*)d_in[10];
  const float* ln2_w  = (const float*)d_in[11];
  const float* ln2_b  = (const float*)d_in[12];
  const float* W1     = (const float*)d_in[13];
  const float* b1     = (const float*)d_in[14];
  const float* W2     = (const float*)d_in[15];
  const float* b2     = (const float*)d_in[16];
  float* out = (float*)d_out;

  // Workspace layout (~117 MB)
  char* p = (char*)d_ws;
  ushort* h     = (ushort*)p;  p += (size_t)Mrows * Cdim * 2;   // reused as h2
  ushort* Qb    = (ushort*)p;                                    // 12.6 MB
  float*  x1    = (float*)p;   p += (size_t)Mrows * HSd * Hh * 2;  // x1 aliases Qb+Kb
  ushort* Kb    = (ushort*)p;  p += (size_t)Mrows * HSd * Hh * 2;
  ushort* Vtb   = (ushort*)p;  p += (size_t)Mrows * HSd * Hh * 2;
  ushort* Oc    = (ushort*)p;  p += (size_t)Mrows * Cdim * 2;
  ushort* g     = (ushort*)p;  p += (size_t)Mrows * Cffn * 2;
  ushort* WqkvT = (ushort*)p;  p += (size_t)Nqkv * Cdim * 2;
  ushort* WprojT= (ushort*)p;  p += (size_t)Cdim * Cdim * 2;
  ushort* W1T   = (ushort*)p;  p += (size_t)Cffn * Cdim * 2;
  ushort* W2T   = (ushort*)p;  p += (size_t)Cdim * Cffn * 2;
  float*  bqkv  = (float*)p;   p += (size_t)Nqkv * 4;
  ushort* h2 = h;

  dim3 blk(256);
  dim3 tblk(32, 8);

  // Weight transpose-casts to bf16 [N][K]
  tcast_kernel<<<dim3(2, 12, 6), tblk, 0, stream>>>(Wq, WqkvT,            384, 64);
  tcast_kernel<<<dim3(2, 12, 6), tblk, 0, stream>>>(Wk, WqkvT + 384*384,  384, 64);
  tcast_kernel<<<dim3(2, 12, 6), tblk, 0, stream>>>(Wv, WqkvT + 768*384,  384, 64);
  tcast_kernel<<<dim3(12, 12, 1), tblk, 0, stream>>>(Wproj, WprojT, 384, 384);
  tcast_kernel<<<dim3(48, 12, 1), tblk, 0, stream>>>(W1, W1T, 384, 1536);
  tcast_kernel<<<dim3(12, 48, 1), tblk, 0, stream>>>(W2, W2T, 1536, 384);
  bias_concat_kernel<<<dim3(5), blk, 0, stream>>>(bq, bk, bv, bqkv);

  // 1. LN1 -> h (bf16)
  ln_kernel<<<dim3(Mrows / 4), blk, 0, stream>>>(x, ln1_w, ln1_b, h, Mrows);

  // 2. QKV fused GEMM, epilogue scatters Q/K [BH][T][64] and V^T [BH][64][T]
  mfma_gemm<3><<<dim3(Nqkv / 128, Mrows / 128), blk, 0, stream>>>(
      h, WqkvT, bqkv, nullptr, Qb, Kb, Vtb, Mrows, Nqkv, Cdim);

  // 3. MFMA flash attention -> Oc (bf16, concat layout)
  attn_kernel<<<dim3(Bsz * Hh, 4), blk, 0, stream>>>(Qb, Kb, Vtb, Oc);

  // 4. x1 = x + Oc @ Wproj + bproj (fp32)
  mfma_gemm<1><<<dim3(Cdim / 128, Mrows / 128), blk, 0, stream>>>(
      Oc, WprojT, bproj, x, x1, nullptr, nullptr, Mrows, Cdim, Cdim);

  // 5. LN2 -> h2 (bf16)
  ln_kernel<<<dim3(Mrows / 4), blk, 0, stream>>>(x1, ln2_w, ln2_b, h2, Mrows);

  // 6. g = gelu(h2 @ W1 + b1) (bf16)
  mfma_gemm<2><<<dim3(Cffn / 128, Mrows / 128), blk, 0, stream>>>(
      h2, W1T, b1, nullptr, g, nullptr, nullptr, Mrows, Cffn, Cdim);

  // 7. out = x1 + g @ W2 + b2 (fp32)
  mfma_gemm<1><<<dim3(Cdim / 128, Mrows / 128), blk, 0, stream>>>(
      g, W2T, b2, x1, out, nullptr, nullptr, Mrows, Cdim, Cffn);
}

// Round 4
// 275.543 us; speedup vs baseline: 4.2391x; 1.1293x over previous
//
#include <hip/hip_runtime.h>
#include <math.h>

// Problem constants
constexpr int Bsz  = 64;
constexpr int Tseq = 256;
constexpr int Cdim = 384;
constexpr int Hh   = 6;
constexpr int HSd  = 64;
constexpr int Mrows = Bsz * Tseq;        // 16384
constexpr int Cffn  = 4 * Cdim;          // 1536
constexpr int Nqkv  = 3 * Cdim;          // 1152

typedef __attribute__((ext_vector_type(8))) short short8;  // 8 bf16 = 4 VGPRs
typedef __attribute__((ext_vector_type(4))) float f32x4;

// fp32 -> bf16 round-to-nearest-even
__device__ __forceinline__ ushort f2bf(float x) {
  union { float f; uint u; } a; a.f = x;
  uint r = a.u + 0x7fffu + ((a.u >> 16) & 1u);
  return (ushort)(r >> 16);
}

// ---------------------------------------------------------------------------
// Fused prep: all weight transpose-casts (fp32 [R][S] -> bf16 [S][R]) + bias
// concat, one launch. Blocks 0..1727 = 32x32 transpose tiles; 1728..1732 bias.
// ---------------------------------------------------------------------------
__global__ __launch_bounds__(256) void prep_kernel(
    const float* __restrict__ Wq, const float* __restrict__ Wk,
    const float* __restrict__ Wv, const float* __restrict__ Wproj,
    const float* __restrict__ W1, const float* __restrict__ W2,
    const float* __restrict__ bq, const float* __restrict__ bk,
    const float* __restrict__ bv,
    ushort* __restrict__ WqkvT, ushort* __restrict__ WprojT,
    ushort* __restrict__ W1T, ushort* __restrict__ W2T,
    float* __restrict__ bqkv) {
  const int bid = blockIdx.x;
  if (bid >= 1728) {  // bias concat
    int i = (bid - 1728) * 256 + threadIdx.x;
    if (i < Nqkv)
      bqkv[i] = (i < 384) ? bq[i] : (i < 768) ? bk[i - 384] : bv[i - 768];
    return;
  }
  const int tx = threadIdx.x & 31, ty = threadIdx.x >> 5;  // 32 x 8
  const float* src; ushort* dst; int R, S, r0, s0;
  if (bid < 432) {           // Wq/Wk/Wv: [6][384][64] each -> rows of WqkvT
    int which = bid / 144, rem = bid % 144;
    const float* W = (which == 0) ? Wq : (which == 1) ? Wk : Wv;
    int bz = rem / 24, t = rem % 24;
    R = 384; S = 64;
    src = W + (size_t)bz * R * S;
    dst = WqkvT + (size_t)which * 384 * 384 + (size_t)bz * R * S;
    r0 = (t >> 1) * 32; s0 = (t & 1) * 32;
  } else if (bid < 576) {    // Wproj 384x384
    int rem = bid - 432; R = 384; S = 384; src = Wproj; dst = WprojT;
    r0 = (rem / 12) * 32; s0 = (rem % 12) * 32;
  } else if (bid < 1152) {   // W1 384x1536
    int rem = bid - 576; R = 384; S = 1536; src = W1; dst = W1T;
    r0 = (rem / 48) * 32; s0 = (rem % 48) * 32;
  } else {                   // W2 1536x384
    int rem = bid - 1152; R = 1536; S = 384; src = W2; dst = W2T;
    r0 = (rem / 12) * 32; s0 = (rem % 12) * 32;
  }
  __shared__ float t[32][33];
#pragma unroll
  for (int i = 0; i < 32; i += 8)
    t[ty + i][tx] = src[(size_t)(r0 + ty + i) * S + s0 + tx];
  __syncthreads();
#pragma unroll
  for (int i = 0; i < 32; i += 8)
    dst[(size_t)(s0 + ty + i) * R + r0 + tx] = f2bf(t[tx][ty + i]);
}

// ---------------------------------------------------------------------------
// LayerNorm: one wave per row of 384; 4 rows per block. bf16 output.
// ---------------------------------------------------------------------------
__global__ __launch_bounds__(256) void ln_kernel(
    const float* __restrict__ x, const float* __restrict__ w,
    const float* __restrict__ b, ushort* __restrict__ out, int nrows) {
  int row  = blockIdx.x * 4 + (threadIdx.x >> 6);
  int lane = threadIdx.x & 63;
  if (row >= nrows) return;
  const float* xr = x + (size_t)row * Cdim;
  float v[6];
  float s = 0.f;
#pragma unroll
  for (int i = 0; i < 6; ++i) { v[i] = xr[lane + 64 * i]; s += v[i]; }
#pragma unroll
  for (int off = 32; off > 0; off >>= 1) s += __shfl_xor(s, off, 64);
  float mean = s * (1.f / Cdim);
  float sq = 0.f;
#pragma unroll
  for (int i = 0; i < 6; ++i) { float d = v[i] - mean; sq += d * d; }
#pragma unroll
  for (int off = 32; off > 0; off >>= 1) sq += __shfl_xor(sq, off, 64);
  float rstd = rsqrtf(sq * (1.f / Cdim) + 1e-5f);
  ushort* orow = out + (size_t)row * Cdim;
#pragma unroll
  for (int i = 0; i < 6; ++i) {
    int c = lane + 64 * i;
    orow[c] = f2bf((v[i] - mean) * rstd * w[c] + b[c]);
  }
}

// ---------------------------------------------------------------------------
// bf16 MFMA GEMM: C[M,N] = epi(A[M,K] @ Bt[N,K]^T + bias). 128x128 tile,
// BK=32, 4 waves (2x2 of 64x64), 4x4 16x16 MFMAs per wave.
// Epilogue loop order (i, r, j): each row's 64 consecutive cols written as
// one burst -> full cache lines, no partial-line churn.
// EPI: 0 = +bias -> bf16; 1 = +bias+res -> fp32; 2 = gelu -> bf16
//      3 = QKV split: Q,K,V each -> [BH][T][64] bf16 (coalesced)
// ---------------------------------------------------------------------------
template <int EPI>
__global__ __launch_bounds__(256) void mfma_gemm(
    const ushort* __restrict__ A, const ushort* __restrict__ Bt,
    const float* __restrict__ bias, const float* __restrict__ res,
    void* __restrict__ Cout, void* __restrict__ C2, void* __restrict__ C3,
    int M, int N, int K) {
  __shared__ ushort Als[128 * 32];
  __shared__ ushort Bls[128 * 32];
  const int tid = threadIdx.x;
  const int m0 = blockIdx.y * 128, n0 = blockIdx.x * 128;

  const int lane = tid & 63;
  const int w    = tid >> 6;
  const int wr   = (w >> 1) * 64;
  const int wc   = (w & 1) * 64;
  const int lm   = lane & 15;
  const int kq   = (lane >> 4) * 8;
  const int rq   = (lane >> 4) * 4;

  const int c0 = tid, c1 = tid + 256;
  const int wbase = (tid & ~63) * 8;

  f32x4 acc[4][4] = {};

  for (int k0 = 0; k0 < K; k0 += 32) {
    const ushort* gA0 = A  + (size_t)(m0 + (c0 >> 2)) * K + k0 + (c0 & 3) * 8;
    const ushort* gA1 = A  + (size_t)(m0 + (c1 >> 2)) * K + k0 + (c1 & 3) * 8;
    const ushort* gB0 = Bt + (size_t)(n0 + (c0 >> 2)) * K + k0 + (c0 & 3) * 8;
    const ushort* gB1 = Bt + (size_t)(n0 + (c1 >> 2)) * K + k0 + (c1 & 3) * 8;
    __syncthreads();
    __builtin_amdgcn_global_load_lds(
        (const __attribute__((address_space(1))) uint*)gA0,
        (__attribute__((address_space(3))) uint*)(Als + wbase), 16, 0, 0);
    __builtin_amdgcn_global_load_lds(
        (const __attribute__((address_space(1))) uint*)gA1,
        (__attribute__((address_space(3))) uint*)(Als + wbase + 2048), 16, 0, 0);
    __builtin_amdgcn_global_load_lds(
        (const __attribute__((address_space(1))) uint*)gB0,
        (__attribute__((address_space(3))) uint*)(Bls + wbase), 16, 0, 0);
    __builtin_amdgcn_global_load_lds(
        (const __attribute__((address_space(1))) uint*)gB1,
        (__attribute__((address_space(3))) uint*)(Bls + wbase + 2048), 16, 0, 0);
    __syncthreads();

    short8 af[4], bf[4];
#pragma unroll
    for (int i = 0; i < 4; ++i)
      af[i] = *(const short8*)&Als[(wr + i * 16 + lm) * 32 + kq];
#pragma unroll
    for (int j = 0; j < 4; ++j)
      bf[j] = *(const short8*)&Bls[(wc + j * 16 + lm) * 32 + kq];
#pragma unroll
    for (int i = 0; i < 4; ++i)
#pragma unroll
      for (int j = 0; j < 4; ++j)
        acc[i][j] = __builtin_amdgcn_mfma_f32_16x16x32_bf16(af[i], bf[j],
                                                            acc[i][j], 0, 0, 0);
  }

  float bb[4];
#pragma unroll
  for (int j = 0; j < 4; ++j) bb[j] = bias[n0 + wc + j * 16 + lm];

#pragma unroll
  for (int i = 0; i < 4; ++i) {
#pragma unroll
    for (int r = 0; r < 4; ++r) {
      const int row = m0 + wr + i * 16 + rq + r;
      if (EPI == 1) {
        const float* resrow = res + (size_t)row * N + n0 + wc;
        float* crow = (float*)Cout + (size_t)row * N + n0 + wc;
#pragma unroll
        for (int j = 0; j < 4; ++j)
          crow[j * 16 + lm] = acc[i][j][r] + bb[j] + resrow[j * 16 + lm];
      } else if (EPI == 3) {
        const int bb_ = row >> 8, tt = row & 255;
#pragma unroll
        for (int j = 0; j < 4; ++j) {
          const int colb = n0 + wc + j * 16;
          const int sec = colb / 384, cc = colb % 384;
          const int hh = cc >> 6, db = (cc & 63) + lm;
          ushort* dstp = (sec == 0) ? (ushort*)Cout
                       : (sec == 1) ? (ushort*)C2 : (ushort*)C3;
          dstp[((size_t)(bb_ * Hh + hh) * Tseq + tt) * HSd + db] =
              f2bf(acc[i][j][r] + bb[j]);
        }
      } else {
        ushort* crow = (ushort*)Cout + (size_t)row * N + n0 + wc;
#pragma unroll
        for (int j = 0; j < 4; ++j) {
          float v = acc[i][j][r] + bb[j];
          if (EPI == 2) v = 0.5f * v * (1.f + erff(v * 0.70710678118654752f));
          crow[j * 16 + lm] = f2bf(v);
        }
      }
    }
  }
}

// ---------------------------------------------------------------------------
// MFMA flash attention. Block = (b*H+h, q-tile of 64 rows), 4 waves; wave w
// owns a 16-row Q strip. V arrives row-major [BH][T][64] and is transposed
// into LDS during staging (per-wave fixed dim-chunk, key=lane -> 2-way bank
// aliasing only). Output Oc bf16 [M][384] concat layout.
// ---------------------------------------------------------------------------
__global__ __launch_bounds__(256) void attn_kernel(
    const ushort* __restrict__ Qb, const ushort* __restrict__ Kb,
    const ushort* __restrict__ Vb, ushort* __restrict__ Oc) {
  __shared__ ushort Ks[64 * 80];     // [key][dim]
  __shared__ ushort Vt[64 * 80];     // [dim][key]
  __shared__ ushort Pl[4][16 * 72];  // per-wave P strip [row][key]
  const int bh = blockIdx.x, qt = blockIdx.y;
  const int b = bh / Hh, h = bh % Hh;
  const int tid = threadIdx.x;
  const int w = tid >> 6, lane = tid & 63;
  const int g = lane >> 4, n16 = lane & 15;

  const ushort* qrow = Qb + ((size_t)bh * Tseq + qt * 64 + w * 16 + n16) * HSd;
  short8 qf0 = *(const short8*)(qrow + g * 8);
  short8 qf1 = *(const short8*)(qrow + 32 + g * 8);

  f32x4 oacc[4] = {};
  float m_r[4], l_r[4];
#pragma unroll
  for (int r = 0; r < 4; ++r) { m_r[r] = -1e30f; l_r[r] = 0.f; }

  const int t0 = qt * 64 + w * 16 + g * 4;

  const ushort* Ksrc = Kb + (size_t)bh * Tseq * HSd;
  const ushort* Vsrc = Vb + (size_t)bh * Tseq * HSd;

  for (int st = 0; st <= qt; ++st) {
    __syncthreads();
    for (int c = tid; c < 512; c += 256) {
      // K: coalesced rows
      int kr = c >> 3, kc = (c & 7) * 8;
      *(uint4*)&Ks[kr * 80 + kc] =
          *(const uint4*)&Ksrc[(size_t)(st * 64 + kr) * HSd + kc];
      // V: transpose in-flight; vr = key (lane), vc = dim chunk (wave)
      int vr = c & 63, vc = (c >> 6) * 8;
      uint4 vv = *(const uint4*)&Vsrc[(size_t)(st * 64 + vr) * HSd + vc];
      const ushort* pv = (const ushort*)&vv;
#pragma unroll
      for (int i = 0; i < 8; ++i) Vt[(vc + i) * 80 + vr] = pv[i];
    }
    __syncthreads();

    // S = Q K^T, 4 col tiles
    f32x4 s[4];
#pragma unroll
    for (int ct = 0; ct < 4; ++ct) {
      short8 kf0 = *(const short8*)&Ks[(ct * 16 + n16) * 80 + g * 8];
      short8 kf1 = *(const short8*)&Ks[(ct * 16 + n16) * 80 + 32 + g * 8];
      f32x4 z = {};
      z = __builtin_amdgcn_mfma_f32_16x16x32_bf16(qf0, kf0, z, 0, 0, 0);
      z = __builtin_amdgcn_mfma_f32_16x16x32_bf16(qf1, kf1, z, 0, 0, 0);
      s[ct] = z;
    }

    // scale + causal mask
#pragma unroll
    for (int ct = 0; ct < 4; ++ct) {
      const int s_col = st * 64 + ct * 16 + n16;
#pragma unroll
      for (int r = 0; r < 4; ++r) {
        float v = s[ct][r] * 0.125f;
        s[ct][r] = (s_col > t0 + r) ? -1e30f : v;
      }
    }

    // online softmax per strip row
#pragma unroll
    for (int r = 0; r < 4; ++r) {
      float m = fmaxf(fmaxf(s[0][r], s[1][r]), fmaxf(s[2][r], s[3][r]));
      m = fmaxf(m, __shfl_xor(m, 1, 64));
      m = fmaxf(m, __shfl_xor(m, 2, 64));
      m = fmaxf(m, __shfl_xor(m, 4, 64));
      m = fmaxf(m, __shfl_xor(m, 8, 64));
      float mnew = fmaxf(m_r[r], m);
      float alpha = __expf(m_r[r] - mnew);
      m_r[r] = mnew;
      float ssum = 0.f;
#pragma unroll
      for (int ct = 0; ct < 4; ++ct) {
        float p = __expf(s[ct][r] - mnew);
        s[ct][r] = p;
        ssum += p;
      }
      ssum += __shfl_xor(ssum, 1, 64);
      ssum += __shfl_xor(ssum, 2, 64);
      ssum += __shfl_xor(ssum, 4, 64);
      ssum += __shfl_xor(ssum, 8, 64);
      l_r[r] = l_r[r] * alpha + ssum;
#pragma unroll
      for (int j = 0; j < 4; ++j) oacc[j][r] *= alpha;
    }

    // P (C-layout) -> per-wave LDS -> A-frags
    ushort* pw = &Pl[w][0];
#pragma unroll
    for (int ct = 0; ct < 4; ++ct)
#pragma unroll
      for (int r = 0; r < 4; ++r)
        pw[(g * 4 + r) * 72 + ct * 16 + n16] = f2bf(s[ct][r]);

    short8 pf0 = *(const short8*)&pw[n16 * 72 + g * 8];
    short8 pf1 = *(const short8*)&pw[n16 * 72 + 32 + g * 8];
#pragma unroll
    for (int j = 0; j < 4; ++j) {
      short8 vf0 = *(const short8*)&Vt[(j * 16 + n16) * 80 + g * 8];
      short8 vf1 = *(const short8*)&Vt[(j * 16 + n16) * 80 + 32 + g * 8];
      oacc[j] = __builtin_amdgcn_mfma_f32_16x16x32_bf16(pf0, vf0, oacc[j], 0, 0, 0);
      oacc[j] = __builtin_amdgcn_mfma_f32_16x16x32_bf16(pf1, vf1, oacc[j], 0, 0, 0);
    }
  }

  float inv[4];
#pragma unroll
  for (int r = 0; r < 4; ++r) inv[r] = 1.f / l_r[r];
  ushort* orow = Oc + ((size_t)(b * Tseq + qt * 64 + w * 16)) * Cdim + h * HSd;
#pragma unroll
  for (int j = 0; j < 4; ++j)
#pragma unroll
    for (int r = 0; r < 4; ++r)
      orow[(size_t)(g * 4 + r) * Cdim + j * 16 + n16] = f2bf(oacc[j][r] * inv[r]);
}

// ---------------------------------------------------------------------------
extern "C" void kernel_launch(void* const* d_in, const int* in_sizes, int n_in,
                              void* d_out, int out_size, void* d_ws, size_t ws_size,
                              hipStream_t stream) {
  const float* x      = (const float*)d_in[0];
  const float* ln1_w  = (const float*)d_in[1];
  const float* ln1_b  = (const float*)d_in[2];
  const float* Wq     = (const float*)d_in[3];
  const float* bq     = (const float*)d_in[4];
  const float* Wk     = (const float*)d_in[5];
  const float* bk     = (const float*)d_in[6];
  const float* Wv     = (const float*)d_in[7];
  const float* bv     = (const float*)d_in[8];
  const float* Wproj  = (const float*)d_in[9];
  const float* bproj  = (const float*)d_in[10];
  const float* ln2_w  = (const float*)d_in[11];
  const float* ln2_b  = (const float*)d_in[12];
  const float* W1     = (const float*)d_in[13];
  const float* b1     = (const float*)d_in[14];
  const float* W2     = (const float*)d_in[15];
  const float* b2     = (const float*)d_in[16];
  float* out = (float*)d_out;

  // Workspace layout (~117 MB)
  char* p = (char*)d_ws;
  ushort* h     = (ushort*)p;  p += (size_t)Mrows * Cdim * 2;   // reused as h2
  ushort* Qb    = (ushort*)p;                                    // 12.6 MB
  float*  x1    = (float*)p;   p += (size_t)Mrows * HSd * Hh * 2;  // aliases Qb+Kb
  ushort* Kb    = (ushort*)p;  p += (size_t)Mrows * HSd * Hh * 2;
  ushort* Vb    = (ushort*)p;  p += (size_t)Mrows * HSd * Hh * 2;
  ushort* Oc    = (ushort*)p;  p += (size_t)Mrows * Cdim * 2;
  ushort* g     = (ushort*)p;  p += (size_t)Mrows * Cffn * 2;
  ushort* WqkvT = (ushort*)p;  p += (size_t)Nqkv * Cdim * 2;
  ushort* WprojT= (ushort*)p;  p += (size_t)Cdim * Cdim * 2;
  ushort* W1T   = (ushort*)p;  p += (size_t)Cffn * Cdim * 2;
  ushort* W2T   = (ushort*)p;  p += (size_t)Cdim * Cffn * 2;
  float*  bqkv  = (float*)p;   p += (size_t)Nqkv * 4;
  ushort* h2 = h;

  dim3 blk(256);

  // 0. Fused weight prep (transpose-casts + bias concat), one launch
  prep_kernel<<<dim3(1733), blk, 0, stream>>>(Wq, Wk, Wv, Wproj, W1, W2,
                                              bq, bk, bv,
                                              WqkvT, WprojT, W1T, W2T, bqkv);

  // 1. LN1 -> h (bf16)
  ln_kernel<<<dim3(Mrows / 4), blk, 0, stream>>>(x, ln1_w, ln1_b, h, Mrows);

  // 2. QKV fused GEMM, epilogue splits Q/K/V into [BH][T][64] (coalesced)
  mfma_gemm<3><<<dim3(Nqkv / 128, Mrows / 128), blk, 0, stream>>>(
      h, WqkvT, bqkv, nullptr, Qb, Kb, Vb, Mrows, Nqkv, Cdim);

  // 3. MFMA flash attention -> Oc (bf16, concat layout)
  attn_kernel<<<dim3(Bsz * Hh, 4), blk, 0, stream>>>(Qb, Kb, Vb, Oc);

  // 4. x1 = x + Oc @ Wproj + bproj (fp32)
  mfma_gemm<1><<<dim3(Cdim / 128, Mrows / 128), blk, 0, stream>>>(
      Oc, WprojT, bproj, x, x1, nullptr, nullptr, Mrows, Cdim, Cdim);

  // 5. LN2 -> h2 (bf16)
  ln_kernel<<<dim3(Mrows / 4), blk, 0, stream>>>(x1, ln2_w, ln2_b, h2, Mrows);

  // 6. g = gelu(h2 @ W1 + b1) (bf16)
  mfma_gemm<2><<<dim3(Cffn / 128, Mrows / 128), blk, 0, stream>>>(
      h2, W1T, b1, nullptr, g, nullptr, nullptr, Mrows, Cffn, Cdim);

  // 7. out = x1 + g @ W2 + b2 (fp32)
  mfma_gemm<1><<<dim3(Cdim / 128, Mrows / 128), blk, 0, stream>>>(
      g, W2T, b2, x1, out, nullptr, nullptr, Mrows, Cdim, Cffn);
}

// Round 5
// 273.084 us; speedup vs baseline: 4.2773x; 1.0090x over previous
//
#include <hip/hip_runtime.h>
#include <math.h>

// Problem constants
constexpr int Bsz  = 64;
constexpr int Tseq = 256;
constexpr int Cdim = 384;
constexpr int Hh   = 6;
constexpr int HSd  = 64;
constexpr int Mrows = Bsz * Tseq;        // 16384
constexpr int Cffn  = 4 * Cdim;          // 1536
constexpr int Nqkv  = 3 * Cdim;          // 1152

typedef __attribute__((ext_vector_type(8))) short short8;  // 8 bf16 = 4 VGPRs
typedef __attribute__((ext_vector_type(4))) float f32x4;

// fp32 -> bf16 round-to-nearest-even
__device__ __forceinline__ ushort f2bf(float x) {
  union { float f; uint u; } a; a.f = x;
  uint r = a.u + 0x7fffu + ((a.u >> 16) & 1u);
  return (ushort)(r >> 16);
}

// ---------------------------------------------------------------------------
// Fused prep: all weight transpose-casts (fp32 [R][S] -> bf16 [S][R]) + bias
// concat, one launch. Blocks 0..1727 = 32x32 transpose tiles; 1728..1732 bias.
// ---------------------------------------------------------------------------
__global__ __launch_bounds__(256) void prep_kernel(
    const float* __restrict__ Wq, const float* __restrict__ Wk,
    const float* __restrict__ Wv, const float* __restrict__ Wproj,
    const float* __restrict__ W1, const float* __restrict__ W2,
    const float* __restrict__ bq, const float* __restrict__ bk,
    const float* __restrict__ bv,
    ushort* __restrict__ WqkvT, ushort* __restrict__ WprojT,
    ushort* __restrict__ W1T, ushort* __restrict__ W2T,
    float* __restrict__ bqkv) {
  const int bid = blockIdx.x;
  if (bid >= 1728) {  // bias concat
    int i = (bid - 1728) * 256 + threadIdx.x;
    if (i < Nqkv)
      bqkv[i] = (i < 384) ? bq[i] : (i < 768) ? bk[i - 384] : bv[i - 768];
    return;
  }
  const int tx = threadIdx.x & 31, ty = threadIdx.x >> 5;  // 32 x 8
  const float* src; ushort* dst; int R, S, r0, s0;
  if (bid < 432) {           // Wq/Wk/Wv: [6][384][64] each -> rows of WqkvT
    int which = bid / 144, rem = bid % 144;
    const float* W = (which == 0) ? Wq : (which == 1) ? Wk : Wv;
    int bz = rem / 24, t = rem % 24;
    R = 384; S = 64;
    src = W + (size_t)bz * R * S;
    dst = WqkvT + (size_t)which * 384 * 384 + (size_t)bz * R * S;
    r0 = (t >> 1) * 32; s0 = (t & 1) * 32;
  } else if (bid < 576) {    // Wproj 384x384
    int rem = bid - 432; R = 384; S = 384; src = Wproj; dst = WprojT;
    r0 = (rem / 12) * 32; s0 = (rem % 12) * 32;
  } else if (bid < 1152) {   // W1 384x1536
    int rem = bid - 576; R = 384; S = 1536; src = W1; dst = W1T;
    r0 = (rem / 48) * 32; s0 = (rem % 48) * 32;
  } else {                   // W2 1536x384
    int rem = bid - 1152; R = 1536; S = 384; src = W2; dst = W2T;
    r0 = (rem / 12) * 32; s0 = (rem % 12) * 32;
  }
  __shared__ float t[32][33];
#pragma unroll
  for (int i = 0; i < 32; i += 8)
    t[ty + i][tx] = src[(size_t)(r0 + ty + i) * S + s0 + tx];
  __syncthreads();
#pragma unroll
  for (int i = 0; i < 32; i += 8)
    dst[(size_t)(s0 + ty + i) * R + r0 + tx] = f2bf(t[tx][ty + i]);
}

// ---------------------------------------------------------------------------
// LayerNorm: one wave per row of 384; 4 rows per block. bf16 output.
// ---------------------------------------------------------------------------
__global__ __launch_bounds__(256) void ln_kernel(
    const float* __restrict__ x, const float* __restrict__ w,
    const float* __restrict__ b, ushort* __restrict__ out, int nrows) {
  int row  = blockIdx.x * 4 + (threadIdx.x >> 6);
  int lane = threadIdx.x & 63;
  if (row >= nrows) return;
  const float* xr = x + (size_t)row * Cdim;
  float v[6];
  float s = 0.f;
#pragma unroll
  for (int i = 0; i < 6; ++i) { v[i] = xr[lane + 64 * i]; s += v[i]; }
#pragma unroll
  for (int off = 32; off > 0; off >>= 1) s += __shfl_xor(s, off, 64);
  float mean = s * (1.f / Cdim);
  float sq = 0.f;
#pragma unroll
  for (int i = 0; i < 6; ++i) { float d = v[i] - mean; sq += d * d; }
#pragma unroll
  for (int off = 32; off > 0; off >>= 1) sq += __shfl_xor(sq, off, 64);
  float rstd = rsqrtf(sq * (1.f / Cdim) + 1e-5f);
  ushort* orow = out + (size_t)row * Cdim;
#pragma unroll
  for (int i = 0; i < 6; ++i) {
    int c = lane + 64 * i;
    orow[c] = f2bf((v[i] - mean) * rstd * w[c] + b[c]);
  }
}

// ---------------------------------------------------------------------------
// bf16 MFMA GEMM: C[M,N] = epi(A[M,K] @ Bt[N,K]^T + bias). 128x128 tile,
// BK=32, 4 waves (2x2 of 64x64), 4x4 16x16 MFMAs per wave.
// LDS XOR-swizzle: k-chunk kc of row r lives at slot kc ^ ((r>>1)&3).
// global_load_lds forces LDS slot = lane order, so the *global source* is
// permuted per-thread (constant) and readers apply the same per-lane swizzle.
// Read bank-quad = (4*lm + (g ^ ((lm>>1)&3))) % 8 -> all 8 quads -> 2-way
// aliasing only (free, m136). Was 8-way (2.36M conflict cycles/dispatch).
// EPI: 0 = +bias -> bf16; 1 = +bias+res -> fp32; 2 = gelu -> bf16
//      3 = QKV split: Q,K,V each -> [BH][T][64] bf16 (coalesced)
// ---------------------------------------------------------------------------
template <int EPI>
__global__ __launch_bounds__(256) void mfma_gemm(
    const ushort* __restrict__ A, const ushort* __restrict__ Bt,
    const float* __restrict__ bias, const float* __restrict__ res,
    void* __restrict__ Cout, void* __restrict__ C2, void* __restrict__ C3,
    int M, int N, int K) {
  __shared__ ushort Als[128 * 32];
  __shared__ ushort Bls[128 * 32];
  const int tid = threadIdx.x;
  const int m0 = blockIdx.y * 128, n0 = blockIdx.x * 128;

  const int lane = tid & 63;
  const int w    = tid >> 6;
  const int wr   = (w >> 1) * 64;
  const int wc   = (w & 1) * 64;
  const int lm   = lane & 15;
  const int g    = lane >> 4;
  const int rq   = g * 4;

  const int c0 = tid, c1 = tid + 256;
  const int wbase = (tid & ~63) * 8;
  // global k-chunk this thread fetches (slot = c&3, swizzled by row bit 1):
  const int kcs = (((c0 & 3) ^ ((c0 >> 3) & 3)) * 8);  // same for c0 and c1
  // reader-side swizzled k-offset for fragment loads:
  const int kqs = (g ^ ((lm >> 1) & 3)) * 8;

  f32x4 acc[4][4] = {};

  for (int k0 = 0; k0 < K; k0 += 32) {
    const ushort* gA0 = A  + (size_t)(m0 + (c0 >> 2)) * K + k0 + kcs;
    const ushort* gA1 = A  + (size_t)(m0 + (c1 >> 2)) * K + k0 + kcs;
    const ushort* gB0 = Bt + (size_t)(n0 + (c0 >> 2)) * K + k0 + kcs;
    const ushort* gB1 = Bt + (size_t)(n0 + (c1 >> 2)) * K + k0 + kcs;
    __syncthreads();
    __builtin_amdgcn_global_load_lds(
        (const __attribute__((address_space(1))) uint*)gA0,
        (__attribute__((address_space(3))) uint*)(Als + wbase), 16, 0, 0);
    __builtin_amdgcn_global_load_lds(
        (const __attribute__((address_space(1))) uint*)gA1,
        (__attribute__((address_space(3))) uint*)(Als + wbase + 2048), 16, 0, 0);
    __builtin_amdgcn_global_load_lds(
        (const __attribute__((address_space(1))) uint*)gB0,
        (__attribute__((address_space(3))) uint*)(Bls + wbase), 16, 0, 0);
    __builtin_amdgcn_global_load_lds(
        (const __attribute__((address_space(1))) uint*)gB1,
        (__attribute__((address_space(3))) uint*)(Bls + wbase + 2048), 16, 0, 0);
    __syncthreads();

    short8 af[4], bf[4];
#pragma unroll
    for (int i = 0; i < 4; ++i)
      af[i] = *(const short8*)&Als[(wr + i * 16 + lm) * 32 + kqs];
#pragma unroll
    for (int j = 0; j < 4; ++j)
      bf[j] = *(const short8*)&Bls[(wc + j * 16 + lm) * 32 + kqs];
#pragma unroll
    for (int i = 0; i < 4; ++i)
#pragma unroll
      for (int j = 0; j < 4; ++j)
        acc[i][j] = __builtin_amdgcn_mfma_f32_16x16x32_bf16(af[i], bf[j],
                                                            acc[i][j], 0, 0, 0);
  }

  float bb[4];
#pragma unroll
  for (int j = 0; j < 4; ++j) bb[j] = bias[n0 + wc + j * 16 + lm];

#pragma unroll
  for (int i = 0; i < 4; ++i) {
#pragma unroll
    for (int r = 0; r < 4; ++r) {
      const int row = m0 + wr + i * 16 + rq + r;
      if (EPI == 1) {
        const float* resrow = res + (size_t)row * N + n0 + wc;
        float* crow = (float*)Cout + (size_t)row * N + n0 + wc;
#pragma unroll
        for (int j = 0; j < 4; ++j)
          crow[j * 16 + lm] = acc[i][j][r] + bb[j] + resrow[j * 16 + lm];
      } else if (EPI == 3) {
        const int bb_ = row >> 8, tt = row & 255;
#pragma unroll
        for (int j = 0; j < 4; ++j) {
          const int colb = n0 + wc + j * 16;
          const int sec = colb / 384, cc = colb % 384;
          const int hh = cc >> 6, db = (cc & 63) + lm;
          ushort* dstp = (sec == 0) ? (ushort*)Cout
                       : (sec == 1) ? (ushort*)C2 : (ushort*)C3;
          dstp[((size_t)(bb_ * Hh + hh) * Tseq + tt) * HSd + db] =
              f2bf(acc[i][j][r] + bb[j]);
        }
      } else {
        ushort* crow = (ushort*)Cout + (size_t)row * N + n0 + wc;
#pragma unroll
        for (int j = 0; j < 4; ++j) {
          float v = acc[i][j][r] + bb[j];
          if (EPI == 2) v = 0.5f * v * (1.f + erff(v * 0.70710678118654752f));
          crow[j * 16 + lm] = f2bf(v);
        }
      }
    }
  }
}

// ---------------------------------------------------------------------------
// MFMA flash attention. Block = (b*H+h, q-tile of 64 rows), 4 waves; wave w
// owns a 16-row Q strip. LDS stride 72 ushorts (144 B = 9 bank-quads): frag
// read quad = (n16+g)%8 -> conflict-free (stride 80 was 4-way).
// V transposed into LDS during staging. Output Oc bf16 [M][384] concat.
// ---------------------------------------------------------------------------
__global__ __launch_bounds__(256) void attn_kernel(
    const ushort* __restrict__ Qb, const ushort* __restrict__ Kb,
    const ushort* __restrict__ Vb, ushort* __restrict__ Oc) {
  __shared__ ushort Ks[64 * 72];     // [key][dim]
  __shared__ ushort Vt[64 * 72];     // [dim][key]
  __shared__ ushort Pl[4][16 * 72];  // per-wave P strip [row][key]
  const int bh = blockIdx.x, qt = blockIdx.y;
  const int b = bh / Hh, h = bh % Hh;
  const int tid = threadIdx.x;
  const int w = tid >> 6, lane = tid & 63;
  const int g = lane >> 4, n16 = lane & 15;

  const ushort* qrow = Qb + ((size_t)bh * Tseq + qt * 64 + w * 16 + n16) * HSd;
  short8 qf0 = *(const short8*)(qrow + g * 8);
  short8 qf1 = *(const short8*)(qrow + 32 + g * 8);

  f32x4 oacc[4] = {};
  float m_r[4], l_r[4];
#pragma unroll
  for (int r = 0; r < 4; ++r) { m_r[r] = -1e30f; l_r[r] = 0.f; }

  const int t0 = qt * 64 + w * 16 + g * 4;

  const ushort* Ksrc = Kb + (size_t)bh * Tseq * HSd;
  const ushort* Vsrc = Vb + (size_t)bh * Tseq * HSd;

  for (int st = 0; st <= qt; ++st) {
    __syncthreads();
    for (int c = tid; c < 512; c += 256) {
      // K: coalesced rows
      int kr = c >> 3, kc = (c & 7) * 8;
      *(uint4*)&Ks[kr * 72 + kc] =
          *(const uint4*)&Ksrc[(size_t)(st * 64 + kr) * HSd + kc];
      // V: transpose in-flight; vr = key (lane), vc = dim chunk
      int vr = c & 63, vc = (c >> 6) * 8;
      uint4 vv = *(const uint4*)&Vsrc[(size_t)(st * 64 + vr) * HSd + vc];
      const ushort* pv = (const ushort*)&vv;
#pragma unroll
      for (int i = 0; i < 8; ++i) Vt[(vc + i) * 72 + vr] = pv[i];
    }
    __syncthreads();

    // S = Q K^T, 4 col tiles
    f32x4 s[4];
#pragma unroll
    for (int ct = 0; ct < 4; ++ct) {
      short8 kf0 = *(const short8*)&Ks[(ct * 16 + n16) * 72 + g * 8];
      short8 kf1 = *(const short8*)&Ks[(ct * 16 + n16) * 72 + 32 + g * 8];
      f32x4 z = {};
      z = __builtin_amdgcn_mfma_f32_16x16x32_bf16(qf0, kf0, z, 0, 0, 0);
      z = __builtin_amdgcn_mfma_f32_16x16x32_bf16(qf1, kf1, z, 0, 0, 0);
      s[ct] = z;
    }

    // scale + causal mask
#pragma unroll
    for (int ct = 0; ct < 4; ++ct) {
      const int s_col = st * 64 + ct * 16 + n16;
#pragma unroll
      for (int r = 0; r < 4; ++r) {
        float v = s[ct][r] * 0.125f;
        s[ct][r] = (s_col > t0 + r) ? -1e30f : v;
      }
    }

    // online softmax per strip row
#pragma unroll
    for (int r = 0; r < 4; ++r) {
      float m = fmaxf(fmaxf(s[0][r], s[1][r]), fmaxf(s[2][r], s[3][r]));
      m = fmaxf(m, __shfl_xor(m, 1, 64));
      m = fmaxf(m, __shfl_xor(m, 2, 64));
      m = fmaxf(m, __shfl_xor(m, 4, 64));
      m = fmaxf(m, __shfl_xor(m, 8, 64));
      float mnew = fmaxf(m_r[r], m);
      float alpha = __expf(m_r[r] - mnew);
      m_r[r] = mnew;
      float ssum = 0.f;
#pragma unroll
      for (int ct = 0; ct < 4; ++ct) {
        float p = __expf(s[ct][r] - mnew);
        s[ct][r] = p;
        ssum += p;
      }
      ssum += __shfl_xor(ssum, 1, 64);
      ssum += __shfl_xor(ssum, 2, 64);
      ssum += __shfl_xor(ssum, 4, 64);
      ssum += __shfl_xor(ssum, 8, 64);
      l_r[r] = l_r[r] * alpha + ssum;
#pragma unroll
      for (int j = 0; j < 4; ++j) oacc[j][r] *= alpha;
    }

    // P (C-layout) -> per-wave LDS -> A-frags
    ushort* pw = &Pl[w][0];
#pragma unroll
    for (int ct = 0; ct < 4; ++ct)
#pragma unroll
      for (int r = 0; r < 4; ++r)
        pw[(g * 4 + r) * 72 + ct * 16 + n16] = f2bf(s[ct][r]);

    short8 pf0 = *(const short8*)&pw[n16 * 72 + g * 8];
    short8 pf1 = *(const short8*)&pw[n16 * 72 + 32 + g * 8];
#pragma unroll
    for (int j = 0; j < 4; ++j) {
      short8 vf0 = *(const short8*)&Vt[(j * 16 + n16) * 72 + g * 8];
      short8 vf1 = *(const short8*)&Vt[(j * 16 + n16) * 72 + 32 + g * 8];
      oacc[j] = __builtin_amdgcn_mfma_f32_16x16x32_bf16(pf0, vf0, oacc[j], 0, 0, 0);
      oacc[j] = __builtin_amdgcn_mfma_f32_16x16x32_bf16(pf1, vf1, oacc[j], 0, 0, 0);
    }
  }

  float inv[4];
#pragma unroll
  for (int r = 0; r < 4; ++r) inv[r] = 1.f / l_r[r];
  ushort* orow = Oc + ((size_t)(b * Tseq + qt * 64 + w * 16)) * Cdim + h * HSd;
#pragma unroll
  for (int j = 0; j < 4; ++j)
#pragma unroll
    for (int r = 0; r < 4; ++r)
      orow[(size_t)(g * 4 + r) * Cdim + j * 16 + n16] = f2bf(oacc[j][r] * inv[r]);
}

// ---------------------------------------------------------------------------
extern "C" void kernel_launch(void* const* d_in, const int* in_sizes, int n_in,
                              void* d_out, int out_size, void* d_ws, size_t ws_size,
                              hipStream_t stream) {
  const float* x      = (const float*)d_in[0];
  const float* ln1_w  = (const float*)d_in[1];
  const float* ln1_b  = (const float*)d_in[2];
  const float* Wq     = (const float*)d_in[3];
  const float* bq     = (const float*)d_in[4];
  const float* Wk     = (const float*)d_in[5];
  const float* bk     = (const float*)d_in[6];
  const float* Wv     = (const float*)d_in[7];
  const float* bv     = (const float*)d_in[8];
  const float* Wproj  = (const float*)d_in[9];
  const float* bproj  = (const float*)d_in[10];
  const float* ln2_w  = (const float*)d_in[11];
  const float* ln2_b  = (const float*)d_in[12];
  const float* W1     = (const float*)d_in[13];
  const float* b1     = (const float*)d_in[14];
  const float* W2     = (const float*)d_in[15];
  const float* b2     = (const float*)d_in[16];
  float* out = (float*)d_out;

  // Workspace layout (~117 MB)
  char* p = (char*)d_ws;
  ushort* h     = (ushort*)p;  p += (size_t)Mrows * Cdim * 2;   // reused as h2
  ushort* Qb    = (ushort*)p;                                    // 12.6 MB
  float*  x1    = (float*)p;   p += (size_t)Mrows * HSd * Hh * 2;  // aliases Qb+Kb
  ushort* Kb    = (ushort*)p;  p += (size_t)Mrows * HSd * Hh * 2;
  ushort* Vb    = (ushort*)p;  p += (size_t)Mrows * HSd * Hh * 2;
  ushort* Oc    = (ushort*)p;  p += (size_t)Mrows * Cdim * 2;
  ushort* g     = (ushort*)p;  p += (size_t)Mrows * Cffn * 2;
  ushort* WqkvT = (ushort*)p;  p += (size_t)Nqkv * Cdim * 2;
  ushort* WprojT= (ushort*)p;  p += (size_t)Cdim * Cdim * 2;
  ushort* W1T   = (ushort*)p;  p += (size_t)Cffn * Cdim * 2;
  ushort* W2T   = (ushort*)p;  p += (size_t)Cdim * Cffn * 2;
  float*  bqkv  = (float*)p;   p += (size_t)Nqkv * 4;
  ushort* h2 = h;

  dim3 blk(256);

  // 0. Fused weight prep (transpose-casts + bias concat), one launch
  prep_kernel<<<dim3(1733), blk, 0, stream>>>(Wq, Wk, Wv, Wproj, W1, W2,
                                              bq, bk, bv,
                                              WqkvT, WprojT, W1T, W2T, bqkv);

  // 1. LN1 -> h (bf16)
  ln_kernel<<<dim3(Mrows / 4), blk, 0, stream>>>(x, ln1_w, ln1_b, h, Mrows);

  // 2. QKV fused GEMM, epilogue splits Q/K/V into [BH][T][64] (coalesced)
  mfma_gemm<3><<<dim3(Nqkv / 128, Mrows / 128), blk, 0, stream>>>(
      h, WqkvT, bqkv, nullptr, Qb, Kb, Vb, Mrows, Nqkv, Cdim);

  // 3. MFMA flash attention -> Oc (bf16, concat layout)
  attn_kernel<<<dim3(Bsz * Hh, 4), blk, 0, stream>>>(Qb, Kb, Vb, Oc);

  // 4. x1 = x + Oc @ Wproj + bproj (fp32)
  mfma_gemm<1><<<dim3(Cdim / 128, Mrows / 128), blk, 0, stream>>>(
      Oc, WprojT, bproj, x, x1, nullptr, nullptr, Mrows, Cdim, Cdim);

  // 5. LN2 -> h2 (bf16)
  ln_kernel<<<dim3(Mrows / 4), blk, 0, stream>>>(x1, ln2_w, ln2_b, h2, Mrows);

  // 6. g = gelu(h2 @ W1 + b1) (bf16)
  mfma_gemm<2><<<dim3(Cffn / 128, Mrows / 128), blk, 0, stream>>>(
      h2, W1T, b1, nullptr, g, nullptr, nullptr, Mrows, Cffn, Cdim);

  // 7. out = x1 + g @ W2 + b2 (fp32)
  mfma_gemm<1><<<dim3(Cdim / 128, Mrows / 128), blk, 0, stream>>>(
      g, W2T, b2, x1, out, nullptr, nullptr, Mrows, Cdim, Cffn);
}